// Round 4
// baseline (101.974 us; speedup 1.0000x reference)
//
#include <hip/hip_runtime.h>
#include <hip/hip_bf16.h>
#include <stdint.h>

typedef float f32x4 __attribute__((ext_vector_type(4)));
typedef float f32x16 __attribute__((ext_vector_type(16)));
typedef short s16x8 __attribute__((ext_vector_type(8)));
typedef unsigned short u16;

__device__ __forceinline__ u16 f2bf(float f) {
    union { __hip_bfloat16 h; u16 u; } cv;
    cv.h = __float2bfloat16(f);
    return cv.u;
}
__device__ __forceinline__ int pkbf(float lo, float hi) {
    return (int)(unsigned)f2bf(lo) | ((int)(unsigned)f2bf(hi) << 16);
}
__device__ __forceinline__ f32x4 mfma16(s16x8 a, s16x8 b, f32x4 c) {
    return __builtin_amdgcn_mfma_f32_16x16x32_bf16(a, b, c, 0, 0, 0);
}
__device__ __forceinline__ f32x16 mfma32(s16x8 a, s16x8 b, f32x16 c) {
    return __builtin_amdgcn_mfma_f32_32x32x16_bf16(a, b, c, 0, 0, 0);
}
__device__ __forceinline__ float exp2_hw(float x) {
    float r; asm("v_exp_f32 %0, %1" : "=v"(r) : "v"(x)); return r;
}
// lane ^= 16 (within 32-lane groups; xor16 never crosses them)
__device__ __forceinline__ int swz16(int v) {
    return __builtin_amdgcn_ds_swizzle(v, 0x401F);
}
// in lanes 0-31, fetch the value held by lane+32 (hi lanes: don't-care)
__device__ __forceinline__ int pl_hi_to_lo(int v) {
    auto r = __builtin_amdgcn_permlane32_swap(v, v, false, false);
    return r[1]; // [v.hi, v.hi]
}
__device__ __forceinline__ void pl_pair(int a, int b, int* xo, int* yo) {
    auto r = __builtin_amdgcn_permlane32_swap(a, b, false, false);
    *xo = r[0]; // [a.lo, b.lo]
    *yo = r[1]; // [a.hi, b.hi]
}
__device__ __forceinline__ s16x8 frag4(int d0, int d1, int d2, int d3) {
    union { int i[4]; s16x8 v; } u;
    u.i[0] = d0; u.i[1] = d1; u.i[2] = d2; u.i[3] = d3;
    return u.v;
}

// x: (4,512,512,32) f32. Window=4, shift=2, heads=4, d=8.
// 1 wave = 1 window; fully LDS-free (register fragments + permlane/swizzle).
__global__ __launch_bounds__(256, 3) void swin_attn_kernel(
    const float* __restrict__ x,
    const float* __restrict__ Wq, const float* __restrict__ bq,
    const float* __restrict__ Wk, const float* __restrict__ bk,
    const float* __restrict__ Wv, const float* __restrict__ bv,
    const float* __restrict__ Wo, const float* __restrict__ bo,
    float* __restrict__ out)
{
    const int lane = threadIdx.x & 63;
    const int wave = threadIdx.x >> 6;
    const int c16  = lane & 15;
    const int g    = lane >> 4;     // 0..3
    const int hc   = g & 1;         // head-within-pair / column-block bit
    const bool lo32  = (lane < 32);
    const bool rowok = (hc == 0);   // PV A-operand valid lanes (rows 0-15)

    const float qscale = 0.35355339059327373f * 1.4426950408889634f; // 1/sqrt(8)*log2e

    // ---------------- weights in registers ----------------
    // q,k slot map within j-block: slot c=4*gs+i -> (h=c>>2, d=(j&1)*4+(c&3))
    s16x8 wqkv[6];
    #pragma unroll
    for (int j = 0; j < 4; ++j) {
        const float* Wsrc = (j < 2) ? Wq : Wk;
        const float sc = (j < 2) ? qscale : 1.0f;
        const int h = c16 >> 2, d = (j & 1) * 4 + (c16 & 3);
        s16x8 wf;
        #pragma unroll
        for (int jj = 0; jj < 8; ++jj)
            wf[jj] = (short)f2bf(Wsrc[(g * 8 + jj) * 32 + h * 8 + d] * sc);
        wqkv[j] = wf;
    }
    // v slot map: slot c -> (h = jv*2 + (c>>3), d = c&7)
    #pragma unroll
    for (int jv = 0; jv < 2; ++jv) {
        const int h = jv * 2 + (c16 >> 3), d = c16 & 7;
        s16x8 wf;
        #pragma unroll
        for (int jj = 0; jj < 8; ++jj)
            wf[jj] = (short)f2bf(Wv[(g * 8 + jj) * 32 + h * 8 + d]);
        wqkv[4 + jv] = wf;
    }
    // C^T-orientation bias for q,k: rows = outslot 4g+i -> h=g, d=(j&1)*4+i
    f32x4 bias_qk[4];
    #pragma unroll
    for (int j = 0; j < 4; ++j) {
        const float* bsrc = (j < 2) ? bq : bk;
        const float sc = (j < 2) ? qscale : 1.0f;
        #pragma unroll
        for (int i = 0; i < 4; ++i)
            bias_qk[j][i] = bsrc[g * 8 + (j & 1) * 4 + i] * sc;
    }
    f32x4 bias_v[2];
    #pragma unroll
    for (int jv = 0; jv < 2; ++jv) {
        float b = bv[(jv * 2 + (c16 >> 3)) * 8 + (c16 & 7)];
        bias_v[jv] = (f32x4){b, b, b, b};
    }
    // out-proj A-frag: rows cout=j2*16+c16, k-slot (g,jj) -> (h,d)
    s16x8 wo_frag[2];
    f32x4 bo_frag[2];
    #pragma unroll
    for (int j2 = 0; j2 < 2; ++j2) {
        const int cout = j2 * 16 + c16;
        s16x8 wf;
        #pragma unroll
        for (int jj = 0; jj < 8; ++jj) {
            const int h = (g & 1) + 2 * (jj >> 2);
            const int d = 4 * (g >> 1) + (jj & 3);
            wf[jj] = (short)f2bf(Wo[(h * 8 + d) * 32 + cout]);
        }
        wo_frag[j2] = wf;
        #pragma unroll
        for (int i = 0; i < 4; ++i)
            bo_frag[j2][i] = bo[j2 * 16 + 4 * g + i];
    }

    f32x16 zero16;
    #pragma unroll
    for (int i = 0; i < 16; ++i) zero16[i] = 0.0f;

    // softmax over kt + build PV B-frag, all in-register (permlane only)
    auto softmax_pack = [&](const f32x16& S) -> s16x8 {
        float e[8];
        #pragma unroll
        for (int i = 0; i < 8; ++i) {
            float sv = hc ? S[8 + i] : S[i]; // valid diag-block regs
            e[i] = exp2_hw(sv);              // log2e folded into q
        }
        float s = ((e[0] + e[1]) + (e[2] + e[3])) + ((e[4] + e[5]) + (e[6] + e[7]));
        auto rs = __builtin_amdgcn_permlane32_swap(__float_as_int(s), __float_as_int(s), false, false);
        float partner = lo32 ? __int_as_float(rs[1]) : __int_as_float(rs[0]);
        float inv = __builtin_amdgcn_rcpf(s + partner);
        #pragma unroll
        for (int i = 0; i < 8; ++i) e[i] *= inv;
        int dw0 = pkbf(e[0], e[1]), dw1 = pkbf(e[2], e[3]);
        int dw2 = pkbf(e[4], e[5]), dw3 = pkbf(e[6], e[7]);
        int a0, b0, a1, b1;
        pl_pair(dw0, dw2, &a0, &b0);
        pl_pair(dw1, dw3, &a1, &b1);
        return frag4(a0, a1, b0, b1); // k-slots = kt 0..7 (g5=0) / 8..15 (g5=1)
    };

    // ---------------- main loop: 4 windows/wave ----------------
    const int wbase = (blockIdx.x * 4 + wave) * 4;
    long curpix;
    f32x4 px0, px1;
    {
        const int w = wbase;
        const int b = w >> 14, rem = w & 16383, wi = rem >> 7, wj = rem & 127;
        const int row  = (wi * 4 + (c16 >> 2) + 2) & 511;
        const int colp = (wj * 4 + (c16 & 3) + 2) & 511;
        curpix = ((((long)b << 9) + row) * 512 + colp) * 32;
        px0 = *(const f32x4*)(x + curpix + g * 8);
        px1 = *(const f32x4*)(x + curpix + g * 8 + 4);
    }

    #pragma unroll 1
    for (int it = 0; it < 4; ++it) {
        const long pixbase = curpix;
        s16x8 xfrag = frag4(pkbf(px0[0], px0[1]), pkbf(px0[2], px0[3]),
                            pkbf(px1[0], px1[1]), pkbf(px1[2], px1[3]));

        // prefetch next window (wrap at it==3: harmless re-read)
        {
            const int w = wbase + ((it + 1) & 3);
            const int b = w >> 14, rem = w & 16383, wi = rem >> 7, wj = rem & 127;
            const int row  = (wi * 4 + (c16 >> 2) + 2) & 511;
            const int colp = (wj * 4 + (c16 & 3) + 2) & 511;
            const long np = ((((long)b << 9) + row) * 512 + colp) * 32;
            px0 = *(const f32x4*)(x + np + g * 8);
            px1 = *(const f32x4*)(x + np + g * 8 + 4);
            curpix = np;
        }
        f32x4 r0 = *(const f32x4*)(x + pixbase + 4 * g);
        f32x4 r1 = *(const f32x4*)(x + pixbase + 16 + 4 * g);

        // ---- projections (all full K=32) ----
        f32x4 cq0 = mfma16(wqkv[0], xfrag, bias_qk[0]); // lane: token=c16, q slots 4g+i (j=0)
        f32x4 cq1 = mfma16(wqkv[1], xfrag, bias_qk[1]);
        f32x4 ck0 = mfma16(wqkv[2], xfrag, bias_qk[2]);
        f32x4 ck1 = mfma16(wqkv[3], xfrag, bias_qk[3]);
        f32x4 cv0 = mfma16(xfrag, wqkv[4], bias_v[0]);  // lane: vslot=c16, tokens 4g+i
        f32x4 cv1 = mfma16(xfrag, wqkv[5], bias_v[1]);

        // pack to bf16 dwords (lane gs holds head gs' d-pairs for q,k)
        int qd0 = pkbf(cq0[0], cq0[1]), qd1 = pkbf(cq0[2], cq0[3]);
        int qd2 = pkbf(cq1[0], cq1[1]), qd3 = pkbf(cq1[2], cq1[3]);
        int kd0 = pkbf(ck0[0], ck0[1]), kd1 = pkbf(ck0[2], ck0[3]);
        int kd2 = pkbf(ck1[0], ck1[1]), kd3 = pkbf(ck1[2], ck1[3]);
        int ve0 = pkbf(cv0[0], cv0[1]), ve1 = pkbf(cv0[2], cv0[3]);
        int vf0 = pkbf(cv1[0], cv1[1]), vf1 = pkbf(cv1[2], cv1[3]);

        // V partner tokens via lane^16 swizzle (issued early, consumed after softmax)
        int ve0s = swz16(ve0), ve1s = swz16(ve1);
        int vf0s = swz16(vf0), vf1s = swz16(vf1);

        // ---- scores: 2-head-packed 32x32x16, S^T blocks [kt+16hA][qt+16hc] ----
        s16x8 ka1 = frag4(kd0, kd1, kd2, kd3);                   // h0,h1 (lanes<32 matter)
        s16x8 qb1 = frag4(lo32 ? qd0 : 0, lo32 ? qd1 : 0,
                          lo32 ? qd2 : 0, lo32 ? qd3 : 0);       // masked: k slots 8-15 = 0
        s16x8 ka2 = frag4(pl_hi_to_lo(kd0), pl_hi_to_lo(kd1),
                          pl_hi_to_lo(kd2), pl_hi_to_lo(kd3));   // h2,h3 into lanes<32
        int qp0 = pl_hi_to_lo(qd0), qp1 = pl_hi_to_lo(qd1);
        int qp2 = pl_hi_to_lo(qd2), qp3 = pl_hi_to_lo(qd3);
        s16x8 qb2 = frag4(lo32 ? qp0 : 0, lo32 ? qp1 : 0,
                          lo32 ? qp2 : 0, lo32 ? qp3 : 0);

        f32x16 S1 = mfma32(ka1, qb1, zero16); // diag: S_h0, S_h1
        f32x16 S2 = mfma32(ka2, qb2, zero16); // diag: S_h2, S_h3

        // ---- softmax -> P frags (register-only) ----
        s16x8 pf1 = softmax_pack(S1);
        s16x8 pf2 = softmax_pack(S2);

        // ---- PV: 32x32x16, A rows = vslot (h-pair, d), full K=16=kt ----
        s16x8 va1 = frag4(rowok ? ve0 : 0, rowok ? ve1 : 0,
                          rowok ? ve0s : 0, rowok ? ve1s : 0);   // rows 16-31 zeroed
        s16x8 va2 = frag4(rowok ? vf0 : 0, rowok ? vf1 : 0,
                          rowok ? vf0s : 0, rowok ? vf1s : 0);
        f32x16 O1 = mfma32(va1, pf1, zero16); // rows 0-7: h_even d; 8-15: h_odd d
        f32x16 O2 = mfma32(va2, pf2, zero16);

        // ---- out-proj: Out^T = Wo^T O^T (full K=32), + bo + residual ----
        float o1[4], o2[4];
        #pragma unroll
        for (int i = 0; i < 4; ++i) {
            o1[i] = hc ? O1[4 + i] : O1[i]; // O_{hc}[d=4*(g>>1)+i][qt=c16]
            o2[i] = hc ? O2[4 + i] : O2[i]; // O_{2+hc}
        }
        s16x8 ofrag = frag4(pkbf(o1[0], o1[1]), pkbf(o1[2], o1[3]),
                            pkbf(o2[0], o2[1]), pkbf(o2[2], o2[3]));
        f32x4 ci0 = bo_frag[0], ci1 = bo_frag[1];
        #pragma unroll
        for (int i = 0; i < 4; ++i) { ci0[i] += r0[i]; ci1[i] += r1[i]; }
        f32x4 c0 = mfma16(wo_frag[0], ofrag, ci0); // rows cout 4g+i, col token c16
        f32x4 c1 = mfma16(wo_frag[1], ofrag, ci1);
        *(f32x4*)(out + pixbase + 4 * g) = c0;
        *(f32x4*)(out + pixbase + 16 + 4 * g) = c1;
    }
}

extern "C" void kernel_launch(void* const* d_in, const int* in_sizes, int n_in,
                              void* d_out, int out_size, void* d_ws, size_t ws_size,
                              hipStream_t stream) {
    const float* x  = (const float*)d_in[0];
    const float* Wq = (const float*)d_in[1];
    const float* bq = (const float*)d_in[2];
    const float* Wk = (const float*)d_in[3];
    const float* bk = (const float*)d_in[4];
    const float* Wv = (const float*)d_in[5];
    const float* bv = (const float*)d_in[6];
    const float* Wo = (const float*)d_in[7];
    const float* bo = (const float*)d_in[8];
    float* out = (float*)d_out;

    dim3 grid(4096), block(256);
    hipLaunchKernelGGL(swin_attn_kernel, grid, block, 0, stream,
                       x, Wq, bq, Wk, bk, Wv, bv, Wo, bo, out);
}

// Round 5
// 66.897 us; speedup vs baseline: 1.5243x; 1.5243x over previous
//
#include <hip/hip_runtime.h>
#include <hip/hip_bf16.h>
#include <stdint.h>

typedef float f32x4 __attribute__((ext_vector_type(4)));
typedef short s16x8 __attribute__((ext_vector_type(8)));
typedef unsigned short u16;
typedef u16 u16x4 __attribute__((ext_vector_type(4)));

__device__ __forceinline__ u16 f2bf(float f) {
    union { __hip_bfloat16 h; u16 u; } cv;
    cv.h = __float2bfloat16(f);
    return cv.u;
}
__device__ __forceinline__ int pkbf(float lo, float hi) {
    return (int)(unsigned)f2bf(lo) | ((int)(unsigned)f2bf(hi) << 16);
}
__device__ __forceinline__ f32x4 mfma16(s16x8 a, s16x8 b, f32x4 c) {
    return __builtin_amdgcn_mfma_f32_16x16x32_bf16(a, b, c, 0, 0, 0);
}
__device__ __forceinline__ float exp2_hw(float x) {
    float r; asm("v_exp_f32 %0, %1" : "=v"(r) : "v"(x)); return r;
}
// lane ^= 16 within 32-lane halves
__device__ __forceinline__ int swz16(int v) {
    return __builtin_amdgcn_ds_swizzle(v, 0x401F);
}
// verified (R4 passed): swap(a,b) -> r[0] = [a.lo | b.lo], r[1] = [a.hi | b.hi]
// lo_to_hi: lanes<32 keep own value; lanes>=32 receive (lane-32)'s value
__device__ __forceinline__ int pl_lo_to_hi(int v) {
    auto r = __builtin_amdgcn_permlane32_swap(v, v, false, false);
    return r[0];
}
__device__ __forceinline__ float xor32_other(float v, bool lo32) {
    auto r = __builtin_amdgcn_permlane32_swap(__float_as_int(v), __float_as_int(v), false, false);
    return lo32 ? __int_as_float(r[1]) : __int_as_float(r[0]);
}
__device__ __forceinline__ s16x8 frag4(int d0, int d1, int d2, int d3) {
    union { int i[4]; s16x8 v; } u;
    u.i[0] = d0; u.i[1] = d1; u.i[2] = d2; u.i[3] = d3;
    return u.v;
}
// compiler-only ordering fence; HW order guaranteed by per-wave in-order DS pipe
#define C_FENCE() asm volatile("" ::: "memory")

// x: (4,512,512,32) f32. Window=4, shift=2, heads=4, d=8.
// 1 wave = 1 window (16 tokens), 4 independent waves/block, 4 windows/wave.
__global__ __launch_bounds__(256) void swin_attn_kernel(
    const float* __restrict__ x,
    const float* __restrict__ Wq, const float* __restrict__ bq,
    const float* __restrict__ Wk, const float* __restrict__ bk,
    const float* __restrict__ Wv, const float* __restrict__ bv,
    const float* __restrict__ Wo, const float* __restrict__ bo,
    float* __restrict__ out)
{
    const int lane  = threadIdx.x & 63;
    const int wave  = threadIdx.x >> 6;
    const int c16   = lane & 15;
    const int g     = lane >> 4;
    const bool lo32 = (lane < 32);

    // 18.4 KB/block -> 8 blocks/CU (32 waves, 100% occupancy cap)
    __shared__ __align__(16) u16 qk_bf[4][16][72];  // [wave][token][q0..31,k32..63]
    __shared__ __align__(16) u16 vT_bf[4][32][24];  // [wave][vslot(hd)][token]
    __shared__ __align__(16) u16 p_bf[4][16][24];   // [wave][qt][kt] (reused per head)

    const float qscale = 0.35355339059327373f * 1.4426950408889634f; // 1/sqrt(8)*log2e

    // ---- weights in registers ----
    s16x8 wqkv[6];
    #pragma unroll
    for (int j = 0; j < 6; ++j) {
        const float* Wsrc = (j < 2) ? Wq : (j < 4) ? Wk : Wv;
        const int colW = ((j & 1) << 4) | c16;
        const float sc = (j < 2) ? qscale : 1.0f;
        s16x8 wf;
        #pragma unroll
        for (int jj = 0; jj < 8; ++jj)
            wf[jj] = (short)f2bf(Wsrc[(g * 8 + jj) * 32 + colW] * sc);
        wqkv[j] = wf;
    }
    f32x4 bias_qk[4];
    #pragma unroll
    for (int j = 0; j < 4; ++j) {
        const float* bsrc = (j < 2) ? bq : bk;
        const float sc = (j < 2) ? qscale : 1.0f;
        #pragma unroll
        for (int i = 0; i < 4; ++i)
            bias_qk[j][i] = bsrc[((j & 1) << 4) + 4 * g + i] * sc;
    }
    f32x4 bias_v[2];
    #pragma unroll
    for (int jv = 0; jv < 2; ++jv) {
        float b = bv[jv * 16 + c16];
        bias_v[jv] = (f32x4){b, b, b, b};
    }
    // out-proj A-frag: rows cout=j2*16+c16; k-slot (g,jj) -> h=(g>>1)*2+(jj>>2),
    // d=4*(g&1)+(jj&3)  [matches register ofrag built from PV accumulators]
    s16x8 wo_frag[2];
    f32x4 bo_frag[2];
    #pragma unroll
    for (int j2 = 0; j2 < 2; ++j2) {
        const int cout = j2 * 16 + c16;
        s16x8 wf;
        #pragma unroll
        for (int jj = 0; jj < 8; ++jj) {
            const int h = (g >> 1) * 2 + (jj >> 2);
            const int d = 4 * (g & 1) + (jj & 3);
            wf[jj] = (short)f2bf(Wo[(h * 8 + d) * 32 + cout]);
        }
        wo_frag[j2] = wf;
        #pragma unroll
        for (int i = 0; i < 4; ++i)
            bo_frag[j2][i] = bo[j2 * 16 + 4 * g + i];
    }

    const f32x4 zero4 = {0.f, 0.f, 0.f, 0.f};
    const s16x8 zero8 = {0, 0, 0, 0, 0, 0, 0, 0};

    // prologue: load window 0's x
    const int wbase = (blockIdx.x * 4 + wave) * 4;
    long curpix;
    f32x4 px0, px1;
    {
        const int w = wbase;
        const int b = w >> 14, rem = w & 16383, wi = rem >> 7, wj = rem & 127;
        const int row  = (wi * 4 + (c16 >> 2) + 2) & 511;
        const int colp = (wj * 4 + (c16 & 3) + 2) & 511;
        curpix = ((((long)b << 9) + row) * 512 + colp) * 32;
        px0 = *(const f32x4*)(x + curpix + g * 8);
        px1 = *(const f32x4*)(x + curpix + g * 8 + 4);
    }

    #pragma unroll 1
    for (int it = 0; it < 4; ++it) {
        const long pixbase = curpix;
        s16x8 xfrag = frag4(pkbf(px0[0], px0[1]), pkbf(px0[2], px0[3]),
                            pkbf(px1[0], px1[1]), pkbf(px1[2], px1[3]));

        // ---- phase A: projections -> LDS staging ----
        #pragma unroll
        for (int j = 0; j < 4; ++j) {     // q,k: C^T = W^T X^T (token-major store)
            f32x4 c = mfma16(wqkv[j], xfrag, bias_qk[j]);
            u16x4 qv;
            #pragma unroll
            for (int i = 0; i < 4; ++i) qv[i] = f2bf(c[i]);
            *(u16x4*)&qk_bf[wave][c16][j * 16 + 4 * g] = qv;
        }
        #pragma unroll
        for (int jv = 0; jv < 2; ++jv) {  // v: C = X Wv (vslot-major store)
            f32x4 c = mfma16(xfrag, wqkv[4 + jv], bias_v[jv]);
            u16x4 vv;
            #pragma unroll
            for (int i = 0; i < 4; ++i) vv[i] = f2bf(c[i]);
            *(u16x4*)&vT_bf[wave][jv * 16 + c16][4 * g] = vv;
        }

        // prefetch next window's x (wrap at it==3: harmless re-read)
        {
            const int w = wbase + ((it + 1) & 3);
            const int b = w >> 14, rem = w & 16383, wi = rem >> 7, wj = rem & 127;
            const int row  = (wi * 4 + (c16 >> 2) + 2) & 511;
            const int colp = (wj * 4 + (c16 & 3) + 2) & 511;
            const long np = ((((long)b << 9) + row) * 512 + colp) * 32;
            px0 = *(const f32x4*)(x + np + g * 8);
            px1 = *(const f32x4*)(x + np + g * 8 + 4);
            curpix = np;
        }
        f32x4 r0 = *(const f32x4*)(x + pixbase + 4 * g);
        f32x4 r1 = *(const f32x4*)(x + pixbase + 16 + 4 * g);

        C_FENCE(); // staging -> reads ordered (HW: in-order per-wave DS pipe)

        // ---- phase B: per head, scores + softmax + PV ----
        f32x4 o_acc[4];
        #pragma unroll
        for (int h = 0; h < 4; ++h) {
            s16x8 afrag = zero8, bfrag = zero8;
            if (g == 0) { // k=d<8 only
                afrag = *(const s16x8*)&qk_bf[wave][c16][32 + h * 8]; // K_h[kt=c16][d]
                bfrag = *(const s16x8*)&qk_bf[wave][c16][h * 8];      // Q_h[qt=c16][d]
            }
            f32x4 s = mfma16(afrag, bfrag, zero4); // S^T rows kt=4g+i, col qt=c16

            float e0 = exp2_hw(s[0]), e1 = exp2_hw(s[1]);
            float e2 = exp2_hw(s[2]), e3 = exp2_hw(s[3]);
            float part = (e0 + e1) + (e2 + e3);
            float sum  = part + __int_as_float(swz16(__float_as_int(part)));
            sum += xor32_other(sum, lo32);
            const float inv = __builtin_amdgcn_rcpf(sum);
            u16x4 pv;
            pv[0] = f2bf(e0 * inv); pv[1] = f2bf(e1 * inv);
            pv[2] = f2bf(e2 * inv); pv[3] = f2bf(e3 * inv);
            *(u16x4*)&p_bf[wave][c16][4 * g] = pv; // [qt][kt]
            C_FENCE(); // p write -> p read (in-order)

            s16x8 vfrag = zero8, pfrag = zero8;
            if (g < 2) { // k=kt<16 only
                vfrag = *(const s16x8*)&vT_bf[wave][h * 8 + (c16 & 7)][g * 8];
                pfrag = *(const s16x8*)&p_bf[wave][c16][g * 8];
            }
            o_acc[h] = mfma16(vfrag, pfrag, zero4); // O_h rows d=4g+i (g<2), col qt=c16
            C_FENCE(); // this h's p read before next h's p write (in-order)
        }

        // ---- phase C: ofrag from registers (kills o_bf round-trip) ----
        // lane (c16,g<2) holds O_h[d=4g+i][c16] for all h; move g0->g2, g1->g3
        int t00 = pkbf(o_acc[0][0], o_acc[0][1]), t01 = pkbf(o_acc[0][2], o_acc[0][3]);
        int t10 = pkbf(o_acc[1][0], o_acc[1][1]), t11 = pkbf(o_acc[1][2], o_acc[1][3]);
        int t20 = pkbf(o_acc[2][0], o_acc[2][1]), t21 = pkbf(o_acc[2][2], o_acc[2][3]);
        int t30 = pkbf(o_acc[3][0], o_acc[3][1]), t31 = pkbf(o_acc[3][2], o_acc[3][3]);
        int m20 = pl_lo_to_hi(t20), m21 = pl_lo_to_hi(t21);
        int m30 = pl_lo_to_hi(t30), m31 = pl_lo_to_hi(t31);
        s16x8 ofrag = frag4(lo32 ? t00 : m20, lo32 ? t01 : m21,
                            lo32 ? t10 : m30, lo32 ? t11 : m31);

        // ---- out-proj + bias + residual + store ----
        f32x4 ci0 = bo_frag[0], ci1 = bo_frag[1];
        #pragma unroll
        for (int i = 0; i < 4; ++i) { ci0[i] += r0[i]; ci1[i] += r1[i]; }
        f32x4 c0 = mfma16(wo_frag[0], ofrag, ci0); // rows cout 4g+i, col token c16
        f32x4 c1 = mfma16(wo_frag[1], ofrag, ci1);
        *(f32x4*)(out + pixbase + 4 * g) = c0;
        *(f32x4*)(out + pixbase + 16 + 4 * g) = c1;

        C_FENCE(); // next window's staging writes after this window's reads
    }
}

extern "C" void kernel_launch(void* const* d_in, const int* in_sizes, int n_in,
                              void* d_out, int out_size, void* d_ws, size_t ws_size,
                              hipStream_t stream) {
    const float* x  = (const float*)d_in[0];
    const float* Wq = (const float*)d_in[1];
    const float* bq = (const float*)d_in[2];
    const float* Wk = (const float*)d_in[3];
    const float* bk = (const float*)d_in[4];
    const float* Wv = (const float*)d_in[5];
    const float* bv = (const float*)d_in[6];
    const float* Wo = (const float*)d_in[7];
    const float* bo = (const float*)d_in[8];
    float* out = (float*)d_out;

    dim3 grid(4096), block(256);
    hipLaunchKernelGGL(swin_attn_kernel, grid, block, 0, stream,
                       x, Wq, bq, Wk, bk, Wv, bv, Wo, bo, out);
}